// Round 1
// baseline (190.912 us; speedup 1.0000x reference)
//
#include <hip/hip_runtime.h>

#define BB 32
#define SS 2048
#define DIN 1024
#define DST 512
#define DH 256   // DST/2
#define NST 64   // MAX_STATES
#define SC 32
#define CHUNKS (SS / SC)  // 64

// ---------------- pooling: sum over S with fp32 atomics ----------------
__global__ void pool_kernel(const float* __restrict__ x, float* __restrict__ pooled) {
    int blk = blockIdx.x;
    int b = blk >> 6;        // blk / CHUNKS
    int c = blk & 63;        // blk % CHUNKS
    const float4* xp = (const float4*)(x + ((size_t)b * SS + (size_t)c * SC) * DIN);
    int t = threadIdx.x;     // 256 threads cover 1024 floats as float4
    float4 acc = make_float4(0.f, 0.f, 0.f, 0.f);
#pragma unroll 8
    for (int s = 0; s < SC; ++s) {
        float4 v = xp[s * (DIN / 4) + t];
        acc.x += v.x; acc.y += v.y; acc.z += v.z; acc.w += v.w;
    }
    float* dst = pooled + b * DIN + t * 4;
    atomicAdd(dst + 0, acc.x);
    atomicAdd(dst + 1, acc.y);
    atomicAdd(dst + 2, acc.z);
    atomicAdd(dst + 3, acc.w);
}

__device__ __forceinline__ float dot4(float4 a, float4 b) {
    return a.x * b.x + a.y * b.y + a.z * b.z + a.w * b.w;
}

// ---------------- layer 1: h1 = relu(pooled/S @ W1^T + b1)  [32,512]
//                  hs = relu(bank @ Ws1^T + bs1)             [64,256]
__global__ void layer1_kernel(const float* __restrict__ pooled,
                              const float* __restrict__ W1, const float* __restrict__ b1,
                              const float* __restrict__ Ws1, const float* __restrict__ bs1,
                              const float* __restrict__ bank,
                              float* __restrict__ h1, float* __restrict__ hs) {
    const float invS = 1.0f / (float)SS;
    int bid = blockIdx.x;
    int tid = threadIdx.x;
    if (bid < 16) {
        // 4096 threads: j in [0,512), bq in [0,8) -> 4 batch rows each
        int t = bid * 256 + tid;
        int j = t & 511;
        int bq = t >> 9;
        const float4* w  = (const float4*)(W1 + (size_t)j * DIN);
        const float4* p0 = (const float4*)(pooled + (size_t)(bq * 4 + 0) * DIN);
        const float4* p1 = (const float4*)(pooled + (size_t)(bq * 4 + 1) * DIN);
        const float4* p2 = (const float4*)(pooled + (size_t)(bq * 4 + 2) * DIN);
        const float4* p3 = (const float4*)(pooled + (size_t)(bq * 4 + 3) * DIN);
        float a0 = 0.f, a1 = 0.f, a2 = 0.f, a3 = 0.f;
#pragma unroll 4
        for (int k = 0; k < DIN / 4; ++k) {
            float4 wv = w[k];
            a0 += dot4(wv, p0[k]);
            a1 += dot4(wv, p1[k]);
            a2 += dot4(wv, p2[k]);
            a3 += dot4(wv, p3[k]);
        }
        float bb = b1[j];
        h1[(size_t)(bq * 4 + 0) * DST + j] = fmaxf(a0 * invS + bb, 0.f);
        h1[(size_t)(bq * 4 + 1) * DST + j] = fmaxf(a1 * invS + bb, 0.f);
        h1[(size_t)(bq * 4 + 2) * DST + j] = fmaxf(a2 * invS + bb, 0.f);
        h1[(size_t)(bq * 4 + 3) * DST + j] = fmaxf(a3 * invS + bb, 0.f);
    } else {
        // 4096 threads: j in [0,256), iq in [0,16) -> 4 states each
        int t = (bid - 16) * 256 + tid;
        int j = t & 255;
        int iq = t >> 8;
        const float4* w  = (const float4*)(Ws1 + (size_t)j * DST);
        const float4* s0 = (const float4*)(bank + (size_t)(iq * 4 + 0) * DST);
        const float4* s1 = (const float4*)(bank + (size_t)(iq * 4 + 1) * DST);
        const float4* s2 = (const float4*)(bank + (size_t)(iq * 4 + 2) * DST);
        const float4* s3 = (const float4*)(bank + (size_t)(iq * 4 + 3) * DST);
        float a0 = 0.f, a1 = 0.f, a2 = 0.f, a3 = 0.f;
#pragma unroll 4
        for (int k = 0; k < DST / 4; ++k) {
            float4 wv = w[k];
            a0 += dot4(wv, s0[k]);
            a1 += dot4(wv, s1[k]);
            a2 += dot4(wv, s2[k]);
            a3 += dot4(wv, s3[k]);
        }
        float bb = bs1[j];
        hs[(size_t)(iq * 4 + 0) * DH + j] = fmaxf(a0 + bb, 0.f);
        hs[(size_t)(iq * 4 + 1) * DH + j] = fmaxf(a1 + bb, 0.f);
        hs[(size_t)(iq * 4 + 2) * DH + j] = fmaxf(a2 + bb, 0.f);
        hs[(size_t)(iq * 4 + 3) * DH + j] = fmaxf(a3 + bb, 0.f);
    }
}

// ---------------- layer 2: h2 = relu(h1 @ W2^T + b2) [32,256]; imp logits [64]
__global__ void layer2_kernel(const float* __restrict__ h1,
                              const float* __restrict__ W2, const float* __restrict__ b2,
                              const float* __restrict__ hs,
                              const float* __restrict__ Ws2, const float* __restrict__ bs2,
                              float* __restrict__ h2, float* __restrict__ imp) {
    int bid = blockIdx.x;
    int tid = threadIdx.x;
    if (bid < 8) {
        // 2048 threads: j in [0,256), bq in [0,8) -> 4 batch rows each
        int t = bid * 256 + tid;
        int j = t & 255;
        int bq = t >> 8;
        const float4* w  = (const float4*)(W2 + (size_t)j * DST);
        const float4* p0 = (const float4*)(h1 + (size_t)(bq * 4 + 0) * DST);
        const float4* p1 = (const float4*)(h1 + (size_t)(bq * 4 + 1) * DST);
        const float4* p2 = (const float4*)(h1 + (size_t)(bq * 4 + 2) * DST);
        const float4* p3 = (const float4*)(h1 + (size_t)(bq * 4 + 3) * DST);
        float a0 = 0.f, a1 = 0.f, a2 = 0.f, a3 = 0.f;
#pragma unroll 4
        for (int k = 0; k < DST / 4; ++k) {
            float4 wv = w[k];
            a0 += dot4(wv, p0[k]);
            a1 += dot4(wv, p1[k]);
            a2 += dot4(wv, p2[k]);
            a3 += dot4(wv, p3[k]);
        }
        float bb = b2[j];
        h2[(size_t)(bq * 4 + 0) * DH + j] = fmaxf(a0 + bb, 0.f);
        h2[(size_t)(bq * 4 + 1) * DH + j] = fmaxf(a1 + bb, 0.f);
        h2[(size_t)(bq * 4 + 2) * DH + j] = fmaxf(a2 + bb, 0.f);
        h2[(size_t)(bq * 4 + 3) * DH + j] = fmaxf(a3 + bb, 0.f);
    } else if (tid < NST) {
        int i = tid;
        const float4* hv = (const float4*)(hs + (size_t)i * DH);
        const float4* w  = (const float4*)(Ws2);
        float acc = 0.f;
#pragma unroll 4
        for (int k = 0; k < DH / 4; ++k) acc += dot4(hv[k], w[k]);
        imp[i] = acc + bs2[0];
    }
}

// ---------------- finalize: complexity sigmoid, num_states, ranks, mask ----
__global__ void final_kernel(const float* __restrict__ h2,
                             const float* __restrict__ W3, const float* __restrict__ b3,
                             const float* __restrict__ imp,
                             float* __restrict__ mask_out) {
    __shared__ float s_imp[NST];
    __shared__ int s_num[BB];
    __shared__ int s_rank[NST];
    int tid = threadIdx.x;
    if (tid < NST) s_imp[tid] = imp[tid];

    // complexity: 8 threads per batch row, dot over 256
    int b = tid >> 3;
    int part = tid & 7;
    const float* hrow = h2 + (size_t)b * DH;
    float sum = 0.f;
    for (int k = part; k < DH; k += 8) sum += hrow[k] * W3[k];
    sum += __shfl_xor(sum, 1);
    sum += __shfl_xor(sum, 2);
    sum += __shfl_xor(sum, 4);
    if (part == 0) {
        float z = sum + b3[0];
        float cx = 1.0f / (1.0f + expf(-z));
        float nsf = rintf(4.0f + cx * 60.0f);   // round-half-even = jnp.round
        int ns = (int)nsf;
        ns = min(max(ns, 4), 64);
        s_num[b] = ns;
    }
    __syncthreads();
    if (tid < NST) {
        // rank in descending importance; stable argsort tie-break: lower index wins
        float mine = s_imp[tid];
        int r = 0;
        for (int j = 0; j < NST; ++j) {
            float o = s_imp[j];
            if (o > mine || (o == mine && j < tid)) ++r;
        }
        s_rank[tid] = r;
    }
    __syncthreads();
    for (int idx = tid; idx < BB * NST; idx += 256) {
        int bb = idx >> 6;
        int i = idx & 63;
        mask_out[idx] = (s_rank[i] < s_num[bb]) ? 1.0f : 0.0f;
    }
}

// ---------------- broadcast state_bank -> allocated_states [32,64,512] ------
__global__ void bcast_kernel(const float* __restrict__ bank, float* __restrict__ out) {
    int idx = blockIdx.x * 256 + threadIdx.x;   // 262144 float4 total
    const float4* s = (const float4*)bank;
    float4* d = (float4*)out;
    d[idx] = s[idx & 8191];                     // 8192 float4 = 64*512 floats
}

extern "C" void kernel_launch(void* const* d_in, const int* in_sizes, int n_in,
                              void* d_out, int out_size, void* d_ws, size_t ws_size,
                              hipStream_t stream) {
    const float* x    = (const float*)d_in[0];
    const float* W1   = (const float*)d_in[1];
    const float* b1   = (const float*)d_in[2];
    const float* W2   = (const float*)d_in[3];
    const float* b2   = (const float*)d_in[4];
    const float* W3   = (const float*)d_in[5];
    const float* b3   = (const float*)d_in[6];
    const float* Ws1  = (const float*)d_in[7];
    const float* bs1  = (const float*)d_in[8];
    const float* Ws2  = (const float*)d_in[9];
    const float* bs2  = (const float*)d_in[10];
    const float* bank = (const float*)d_in[11];
    // d_in[12] = temperature: unused — softmax with positive temp is monotonic,
    // so ranks of raw logits equal ranks of importance.

    float* out = (float*)d_out;
    float* mask_out = out + (size_t)BB * NST * DST;  // after allocated_states

    float* ws = (float*)d_ws;
    float* pooled = ws;            // 32768 floats (sum over S, scaled later)
    float* h1 = pooled + 32768;    // 16384
    float* hs = h1 + 16384;        // 16384
    float* h2 = hs + 16384;        // 8192
    float* imp = h2 + 8192;        // 64

    hipMemsetAsync(pooled, 0, 32768 * sizeof(float), stream);
    pool_kernel<<<BB * CHUNKS, 256, 0, stream>>>(x, pooled);
    layer1_kernel<<<32, 256, 0, stream>>>(pooled, W1, b1, Ws1, bs1, bank, h1, hs);
    layer2_kernel<<<9, 256, 0, stream>>>(h1, W2, b2, hs, Ws2, bs2, h2, imp);
    final_kernel<<<1, 256, 0, stream>>>(h2, W3, b3, imp, mask_out);
    bcast_kernel<<<1024, 256, 0, stream>>>(bank, out);
}

// Round 2
// 180.318 us; speedup vs baseline: 1.0588x; 1.0588x over previous
//
#include <hip/hip_runtime.h>

#define BB 32
#define SS 2048
#define DIN 1024
#define DST 512
#define DH 256   // DST/2
#define NST 64   // MAX_STATES
#define SC 32
#define CHUNKS (SS / SC)  // 64

// ---------------- pooling stage 1: partial sums, no atomics ----------------
// grid: BB*CHUNKS blocks x 256 threads; block (b,c) sums 32 seq rows into
// partial[(b*CHUNKS+c)*DIN + d]
__global__ void pool_s1_kernel(const float* __restrict__ x, float* __restrict__ partial) {
    int blk = blockIdx.x;
    int b = blk >> 6;        // blk / CHUNKS
    int c = blk & 63;        // blk % CHUNKS
    const float4* xp = (const float4*)(x + ((size_t)b * SS + (size_t)c * SC) * DIN);
    int t = threadIdx.x;     // 256 threads cover 1024 floats as float4
    float4 acc = make_float4(0.f, 0.f, 0.f, 0.f);
#pragma unroll 8
    for (int s = 0; s < SC; ++s) {
        float4 v = xp[s * (DIN / 4) + t];
        acc.x += v.x; acc.y += v.y; acc.z += v.z; acc.w += v.w;
    }
    float4* dst = (float4*)(partial + (size_t)blk * DIN);
    dst[t] = acc;
}

// ---------------- pooling stage 2: reduce 64 partials per (b,d) ------------
// grid: BB blocks x 256 threads; thread t owns float4 column t of batch b
__global__ void pool_s2_kernel(const float* __restrict__ partial, float* __restrict__ pooled) {
    int b = blockIdx.x;
    int t = threadIdx.x;
    const float4* src = (const float4*)(partial + (size_t)b * CHUNKS * DIN);
    float4 acc = make_float4(0.f, 0.f, 0.f, 0.f);
#pragma unroll 8
    for (int c = 0; c < CHUNKS; ++c) {
        float4 v = src[c * (DIN / 4) + t];
        acc.x += v.x; acc.y += v.y; acc.z += v.z; acc.w += v.w;
    }
    ((float4*)(pooled + (size_t)b * DIN))[t] = acc;
}

__device__ __forceinline__ float dot4(float4 a, float4 b) {
    return a.x * b.x + a.y * b.y + a.z * b.z + a.w * b.w;
}

// ---------------- layer 1: h1 = relu(pooled/S @ W1^T + b1)  [32,512]
//                  hs = relu(bank @ Ws1^T + bs1)             [64,256]
__global__ void layer1_kernel(const float* __restrict__ pooled,
                              const float* __restrict__ W1, const float* __restrict__ b1,
                              const float* __restrict__ Ws1, const float* __restrict__ bs1,
                              const float* __restrict__ bank,
                              float* __restrict__ h1, float* __restrict__ hs) {
    const float invS = 1.0f / (float)SS;
    int bid = blockIdx.x;
    int tid = threadIdx.x;
    if (bid < 16) {
        // 4096 threads: j in [0,512), bq in [0,8) -> 4 batch rows each
        int t = bid * 256 + tid;
        int j = t & 511;
        int bq = t >> 9;
        const float4* w  = (const float4*)(W1 + (size_t)j * DIN);
        const float4* p0 = (const float4*)(pooled + (size_t)(bq * 4 + 0) * DIN);
        const float4* p1 = (const float4*)(pooled + (size_t)(bq * 4 + 1) * DIN);
        const float4* p2 = (const float4*)(pooled + (size_t)(bq * 4 + 2) * DIN);
        const float4* p3 = (const float4*)(pooled + (size_t)(bq * 4 + 3) * DIN);
        float a0 = 0.f, a1 = 0.f, a2 = 0.f, a3 = 0.f;
#pragma unroll 4
        for (int k = 0; k < DIN / 4; ++k) {
            float4 wv = w[k];
            a0 += dot4(wv, p0[k]);
            a1 += dot4(wv, p1[k]);
            a2 += dot4(wv, p2[k]);
            a3 += dot4(wv, p3[k]);
        }
        float bb = b1[j];
        h1[(size_t)(bq * 4 + 0) * DST + j] = fmaxf(a0 * invS + bb, 0.f);
        h1[(size_t)(bq * 4 + 1) * DST + j] = fmaxf(a1 * invS + bb, 0.f);
        h1[(size_t)(bq * 4 + 2) * DST + j] = fmaxf(a2 * invS + bb, 0.f);
        h1[(size_t)(bq * 4 + 3) * DST + j] = fmaxf(a3 * invS + bb, 0.f);
    } else {
        // 4096 threads: j in [0,256), iq in [0,16) -> 4 states each
        int t = (bid - 16) * 256 + tid;
        int j = t & 255;
        int iq = t >> 8;
        const float4* w  = (const float4*)(Ws1 + (size_t)j * DST);
        const float4* s0 = (const float4*)(bank + (size_t)(iq * 4 + 0) * DST);
        const float4* s1 = (const float4*)(bank + (size_t)(iq * 4 + 1) * DST);
        const float4* s2 = (const float4*)(bank + (size_t)(iq * 4 + 2) * DST);
        const float4* s3 = (const float4*)(bank + (size_t)(iq * 4 + 3) * DST);
        float a0 = 0.f, a1 = 0.f, a2 = 0.f, a3 = 0.f;
#pragma unroll 4
        for (int k = 0; k < DST / 4; ++k) {
            float4 wv = w[k];
            a0 += dot4(wv, s0[k]);
            a1 += dot4(wv, s1[k]);
            a2 += dot4(wv, s2[k]);
            a3 += dot4(wv, s3[k]);
        }
        float bb = bs1[j];
        hs[(size_t)(iq * 4 + 0) * DH + j] = fmaxf(a0 + bb, 0.f);
        hs[(size_t)(iq * 4 + 1) * DH + j] = fmaxf(a1 + bb, 0.f);
        hs[(size_t)(iq * 4 + 2) * DH + j] = fmaxf(a2 + bb, 0.f);
        hs[(size_t)(iq * 4 + 3) * DH + j] = fmaxf(a3 + bb, 0.f);
    }
}

// ---------------- layer 2: h2 = relu(h1 @ W2^T + b2) [32,256]; imp logits [64]
__global__ void layer2_kernel(const float* __restrict__ h1,
                              const float* __restrict__ W2, const float* __restrict__ b2,
                              const float* __restrict__ hs,
                              const float* __restrict__ Ws2, const float* __restrict__ bs2,
                              float* __restrict__ h2, float* __restrict__ imp) {
    int bid = blockIdx.x;
    int tid = threadIdx.x;
    if (bid < 8) {
        // 2048 threads: j in [0,256), bq in [0,8) -> 4 batch rows each
        int t = bid * 256 + tid;
        int j = t & 255;
        int bq = t >> 8;
        const float4* w  = (const float4*)(W2 + (size_t)j * DST);
        const float4* p0 = (const float4*)(h1 + (size_t)(bq * 4 + 0) * DST);
        const float4* p1 = (const float4*)(h1 + (size_t)(bq * 4 + 1) * DST);
        const float4* p2 = (const float4*)(h1 + (size_t)(bq * 4 + 2) * DST);
        const float4* p3 = (const float4*)(h1 + (size_t)(bq * 4 + 3) * DST);
        float a0 = 0.f, a1 = 0.f, a2 = 0.f, a3 = 0.f;
#pragma unroll 4
        for (int k = 0; k < DST / 4; ++k) {
            float4 wv = w[k];
            a0 += dot4(wv, p0[k]);
            a1 += dot4(wv, p1[k]);
            a2 += dot4(wv, p2[k]);
            a3 += dot4(wv, p3[k]);
        }
        float bb = b2[j];
        h2[(size_t)(bq * 4 + 0) * DH + j] = fmaxf(a0 + bb, 0.f);
        h2[(size_t)(bq * 4 + 1) * DH + j] = fmaxf(a1 + bb, 0.f);
        h2[(size_t)(bq * 4 + 2) * DH + j] = fmaxf(a2 + bb, 0.f);
        h2[(size_t)(bq * 4 + 3) * DH + j] = fmaxf(a3 + bb, 0.f);
    } else if (tid < NST) {
        int i = tid;
        const float4* hv = (const float4*)(hs + (size_t)i * DH);
        const float4* w  = (const float4*)(Ws2);
        float acc = 0.f;
#pragma unroll 4
        for (int k = 0; k < DH / 4; ++k) acc += dot4(hv[k], w[k]);
        imp[i] = acc + bs2[0];
    }
}

// ---------------- finalize: complexity sigmoid, num_states, ranks, mask ----
__global__ void final_kernel(const float* __restrict__ h2,
                             const float* __restrict__ W3, const float* __restrict__ b3,
                             const float* __restrict__ imp,
                             float* __restrict__ mask_out) {
    __shared__ float s_imp[NST];
    __shared__ int s_num[BB];
    __shared__ int s_rank[NST];
    int tid = threadIdx.x;
    if (tid < NST) s_imp[tid] = imp[tid];

    // complexity: 8 threads per batch row, dot over 256
    int b = tid >> 3;
    int part = tid & 7;
    const float* hrow = h2 + (size_t)b * DH;
    float sum = 0.f;
    for (int k = part; k < DH; k += 8) sum += hrow[k] * W3[k];
    sum += __shfl_xor(sum, 1);
    sum += __shfl_xor(sum, 2);
    sum += __shfl_xor(sum, 4);
    if (part == 0) {
        float z = sum + b3[0];
        float cx = 1.0f / (1.0f + expf(-z));
        float nsf = rintf(4.0f + cx * 60.0f);   // round-half-even = jnp.round
        int ns = (int)nsf;
        ns = min(max(ns, 4), 64);
        s_num[b] = ns;
    }
    __syncthreads();
    if (tid < NST) {
        // rank in descending importance; stable argsort tie-break: lower index wins
        float mine = s_imp[tid];
        int r = 0;
        for (int j = 0; j < NST; ++j) {
            float o = s_imp[j];
            if (o > mine || (o == mine && j < tid)) ++r;
        }
        s_rank[tid] = r;
    }
    __syncthreads();
    for (int idx = tid; idx < BB * NST; idx += 256) {
        int bb = idx >> 6;
        int i = idx & 63;
        mask_out[idx] = (s_rank[i] < s_num[bb]) ? 1.0f : 0.0f;
    }
}

// ---------------- broadcast state_bank -> allocated_states [32,64,512] ------
__global__ void bcast_kernel(const float* __restrict__ bank, float* __restrict__ out) {
    int idx = blockIdx.x * 256 + threadIdx.x;   // 262144 float4 total
    const float4* s = (const float4*)bank;
    float4* d = (float4*)out;
    d[idx] = s[idx & 8191];                     // 8192 float4 = 64*512 floats
}

extern "C" void kernel_launch(void* const* d_in, const int* in_sizes, int n_in,
                              void* d_out, int out_size, void* d_ws, size_t ws_size,
                              hipStream_t stream) {
    const float* x    = (const float*)d_in[0];
    const float* W1   = (const float*)d_in[1];
    const float* b1   = (const float*)d_in[2];
    const float* W2   = (const float*)d_in[3];
    const float* b2   = (const float*)d_in[4];
    const float* W3   = (const float*)d_in[5];
    const float* b3   = (const float*)d_in[6];
    const float* Ws1  = (const float*)d_in[7];
    const float* bs1  = (const float*)d_in[8];
    const float* Ws2  = (const float*)d_in[9];
    const float* bs2  = (const float*)d_in[10];
    const float* bank = (const float*)d_in[11];
    // d_in[12] = temperature: unused — softmax with positive temp is monotonic,
    // so ranks of raw logits equal ranks of importance.

    float* out = (float*)d_out;
    float* mask_out = out + (size_t)BB * NST * DST;  // after allocated_states

    float* ws = (float*)d_ws;
    float* partial = ws;                 // 32*64*1024 = 2,097,152 floats (8 MB)
    float* pooled  = partial + (size_t)BB * CHUNKS * DIN;  // 32768
    float* h1 = pooled + 32768;          // 16384
    float* hs = h1 + 16384;              // 16384
    float* h2 = hs + 16384;              // 8192
    float* imp = h2 + 8192;              // 64

    pool_s1_kernel<<<BB * CHUNKS, 256, 0, stream>>>(x, partial);
    pool_s2_kernel<<<BB, 256, 0, stream>>>(partial, pooled);
    layer1_kernel<<<32, 256, 0, stream>>>(pooled, W1, b1, Ws1, bs1, bank, h1, hs);
    layer2_kernel<<<9, 256, 0, stream>>>(h1, W2, b2, hs, Ws2, bs2, h2, imp);
    final_kernel<<<1, 256, 0, stream>>>(h2, W3, b3, imp, mask_out);
    bcast_kernel<<<1024, 256, 0, stream>>>(bank, out);
}

// Round 3
// 121.914 us; speedup vs baseline: 1.5660x; 1.4791x over previous
//
#include <hip/hip_runtime.h>

#define BB 32
#define SS 2048
#define DIN 1024
#define DST 512
#define DH 256   // DST/2
#define NST 64   // MAX_STATES
#define SC 32
#define CHUNKS (SS / SC)  // 64

__device__ __forceinline__ float dot4(float4 a, float4 b) {
    return a.x * b.x + a.y * b.y + a.z * b.z + a.w * b.w;
}

// K1: pool stage1 (blocks 0..2047) + bcast of state_bank (blocks 2048..3071)
__global__ void k1_pool_bcast(const float* __restrict__ x, const float* __restrict__ bank,
                              float* __restrict__ partial, float* __restrict__ out) {
    int blk = blockIdx.x;
    int t = threadIdx.x;
    if (blk < 2048) {
        int b = blk >> 6;        // batch
        int c = blk & 63;        // chunk
        const float4* xp = (const float4*)(x + ((size_t)b * SS + (size_t)c * SC) * DIN);
        float4 acc = make_float4(0.f, 0.f, 0.f, 0.f);
#pragma unroll
        for (int s = 0; s < SC; ++s) {
            float4 v = xp[s * (DIN / 4) + t];
            acc.x += v.x; acc.y += v.y; acc.z += v.z; acc.w += v.w;
        }
        ((float4*)(partial + (size_t)blk * DIN))[t] = acc;
    } else {
        int idx = (blk - 2048) * 256 + t;          // 262144 float4 total
        ((float4*)out)[idx] = ((const float4*)bank)[idx & 8191];
    }
}

// K2: pool stage2 -> pooled mean (scaled by 1/S)
__global__ void k2_pool2(const float* __restrict__ partial, float* __restrict__ pooled) {
    int b = blockIdx.x;
    int t = threadIdx.x;
    const float4* src = (const float4*)(partial + (size_t)b * CHUNKS * DIN);
    float4 acc = make_float4(0.f, 0.f, 0.f, 0.f);
#pragma unroll 8
    for (int c = 0; c < CHUNKS; ++c) {
        float4 v = src[c * (DIN / 4) + t];
        acc.x += v.x; acc.y += v.y; acc.z += v.z; acc.w += v.w;
    }
    const float invS = 1.0f / (float)SS;
    acc.x *= invS; acc.y *= invS; acc.z *= invS; acc.w *= invS;
    ((float4*)(pooled + (size_t)b * DIN))[t] = acc;
}

// K3: layer1 both paths, weights read ~once total, many blocks.
// blocks 0..63:  h1[b][j] = relu(dot(pooled_b, W1_j) + b1_j), j = g*8 + (t>>5), b = t&31
// blocks 64..127: hs[i][j] = relu(dot(bank_i, Ws1_j) + bs1_j), j = g2*4 + (t>>6), i = t&63
__global__ void k3_layer1(const float* __restrict__ pooled,
                          const float* __restrict__ W1, const float* __restrict__ b1,
                          const float* __restrict__ Ws1, const float* __restrict__ bs1,
                          const float* __restrict__ bank,
                          float* __restrict__ h1, float* __restrict__ hs) {
    int g = blockIdx.x;
    int t = threadIdx.x;
    if (g < 64) {
        int b = t & 31;
        int j = g * 8 + (t >> 5);
        const float4* w = (const float4*)(W1 + (size_t)j * DIN);   // broadcast among 32 lanes
        const float4* p = (const float4*)(pooled + (size_t)b * DIN);
        float a0 = 0.f, a1 = 0.f;
#pragma unroll 8
        for (int k = 0; k < DIN / 4; k += 2) {
            a0 += dot4(w[k], p[k]);
            a1 += dot4(w[k + 1], p[k + 1]);
        }
        h1[(size_t)b * DST + j] = fmaxf(a0 + a1 + b1[j], 0.f);
    } else {
        int g2 = g - 64;
        int i = t & 63;
        int j = g2 * 4 + (t >> 6);
        const float4* w = (const float4*)(Ws1 + (size_t)j * DST);  // broadcast among 64 lanes
        const float4* s = (const float4*)(bank + (size_t)i * DST);
        float a0 = 0.f, a1 = 0.f;
#pragma unroll 8
        for (int k = 0; k < DST / 4; k += 2) {
            a0 += dot4(w[k], s[k]);
            a1 += dot4(w[k + 1], s[k + 1]);
        }
        hs[(size_t)i * DH + j] = fmaxf(a0 + a1 + bs1[j], 0.f);
    }
}

// K4: blocks 0..31: h2 row-chunks + z partial sums (no atomics)
//     block 32:    importance logits
__global__ void k4_layer2(const float* __restrict__ h1,
                          const float* __restrict__ W2, const float* __restrict__ b2,
                          const float* __restrict__ hs,
                          const float* __restrict__ Ws2, const float* __restrict__ bs2,
                          const float* __restrict__ W3,
                          float* __restrict__ zpart, float* __restrict__ imp) {
    int g = blockIdx.x;
    int t = threadIdx.x;
    if (g < 32) {
        __shared__ float s_z[8][32];
        int b = t & 31;
        int jq = t >> 5;
        int j = g * 8 + jq;
        const float4* w = (const float4*)(W2 + (size_t)j * DST);   // broadcast among 32 lanes
        const float4* p = (const float4*)(h1 + (size_t)b * DST);
        float a0 = 0.f, a1 = 0.f;
#pragma unroll 8
        for (int k = 0; k < DST / 4; k += 2) {
            a0 += dot4(w[k], p[k]);
            a1 += dot4(w[k + 1], p[k + 1]);
        }
        float h2v = fmaxf(a0 + a1 + b2[j], 0.f);
        s_z[jq][b] = h2v * W3[j];
        __syncthreads();
        if (t < 32) {
            float z = 0.f;
#pragma unroll
            for (int q = 0; q < 8; ++q) z += s_z[q][t];
            zpart[g * 32 + t] = z;
        }
    } else {
        __shared__ float s_p[4][NST];
        int i = t & 63;
        int part = t >> 6;
        const float4* hv = (const float4*)(hs + (size_t)i * DH + part * 64);
        const float4* wv = (const float4*)(Ws2 + part * 64);       // broadcast among 64 lanes
        float a = 0.f;
#pragma unroll
        for (int m = 0; m < 16; ++m) a += dot4(hv[m], wv[m]);
        s_p[part][i] = a;
        __syncthreads();
        if (t < NST) imp[t] = s_p[0][t] + s_p[1][t] + s_p[2][t] + s_p[3][t] + bs2[0];
    }
}

// K5: finalize — z -> sigmoid -> num_states; ranks from imp; mask write
__global__ void k5_final(const float* __restrict__ zpart, const float* __restrict__ b3,
                         const float* __restrict__ imp, float* __restrict__ mask_out) {
    __shared__ float s_imp[NST];
    __shared__ int s_rank[NST];
    __shared__ int s_num[BB];
    int t = threadIdx.x;
    if (t < NST) s_imp[t] = imp[t];
    if (t < BB) {
        float z = 0.f;
        for (int g = 0; g < 32; ++g) z += zpart[g * 32 + t];
        z += b3[0];
        float cx = 1.0f / (1.0f + expf(-z));
        int ns = (int)rintf(4.0f + cx * 60.0f);   // round-half-even = jnp.round
        s_num[t] = min(max(ns, 4), 64);
    }
    __syncthreads();
    if (t < NST) {
        float mine = s_imp[t];
        int r = 0;
        for (int j = 0; j < NST; ++j) {
            float o = s_imp[j];
            if (o > mine || (o == mine && j < t)) ++r;
        }
        s_rank[t] = r;
    }
    __syncthreads();
    for (int idx = t; idx < BB * NST; idx += 256)
        mask_out[idx] = (s_rank[idx & 63] < s_num[idx >> 6]) ? 1.0f : 0.0f;
}

extern "C" void kernel_launch(void* const* d_in, const int* in_sizes, int n_in,
                              void* d_out, int out_size, void* d_ws, size_t ws_size,
                              hipStream_t stream) {
    const float* x    = (const float*)d_in[0];
    const float* W1   = (const float*)d_in[1];
    const float* b1   = (const float*)d_in[2];
    const float* W2   = (const float*)d_in[3];
    const float* b2   = (const float*)d_in[4];
    const float* W3   = (const float*)d_in[5];
    const float* b3   = (const float*)d_in[6];
    const float* Ws1  = (const float*)d_in[7];
    const float* bs1  = (const float*)d_in[8];
    const float* Ws2  = (const float*)d_in[9];
    const float* bs2  = (const float*)d_in[10];
    const float* bank = (const float*)d_in[11];
    // d_in[12] = temperature: unused — softmax with positive temp is monotonic,
    // so ranks of raw logits equal ranks of importance.

    float* out = (float*)d_out;
    float* mask_out = out + (size_t)BB * NST * DST;

    float* ws = (float*)d_ws;
    float* partial = ws;                                   // 2,097,152 floats (8 MB)
    float* pooled  = partial + (size_t)BB * CHUNKS * DIN;  // 32768
    float* h1  = pooled + BB * DIN;                        // 16384
    float* hs  = h1 + BB * DST;                            // 16384
    float* zpart = hs + NST * DH;                          // 1024
    float* imp = zpart + 1024;                             // 64

    k1_pool_bcast<<<3072, 256, 0, stream>>>(x, bank, partial, out);
    k2_pool2<<<BB, 256, 0, stream>>>(partial, pooled);
    k3_layer1<<<128, 256, 0, stream>>>(pooled, W1, b1, Ws1, bs1, bank, h1, hs);
    k4_layer2<<<33, 256, 0, stream>>>(h1, W2, b2, hs, Ws2, bs2, W3, zpart, imp);
    k5_final<<<1, 256, 0, stream>>>(zpart, b3, imp, mask_out);
}